// Round 11
// baseline (672.490 us; speedup 1.0000x reference)
//
#include <hip/hip_runtime.h>
#include <hip/hip_bf16.h>

#define E_N 640000
#define N_N 40000
#define SCAN_B 157  // ceil(40000/256)
#define AGG_BLOCKS 512
#define CHUNK 2

typedef __attribute__((ext_vector_type(8))) short short8;
typedef __attribute__((ext_vector_type(4))) float f32x4;

static __device__ __forceinline__ unsigned short f2bf(float f) {
  __hip_bfloat16 h = __float2bfloat16(f);
  unsigned short u;
  __builtin_memcpy(&u, &h, 2);
  return u;
}
static __device__ __forceinline__ float bf2f(unsigned short u) {
  return __uint_as_float(((unsigned int)u) << 16);
}

// ---------------- Wt[layer][k][o][i] = bf16(W[k][i][o]); also zero the 2 work counters ----------------
__global__ __launch_bounds__(256) void wtrans_kernel(
    const float* __restrict__ W1, const float* __restrict__ W2,
    unsigned short* __restrict__ Wt, int* __restrict__ ctr) {
  if (blockIdx.x == 0 && threadIdx.x < 2) ctr[threadIdx.x] = 0;
  int t = blockIdx.x * 256 + threadIdx.x;  // 0..204799
  int half = t >= 102400;
  int r = t - (half ? 102400 : 0);
  const float* W = half ? W2 : W1;
  int k = r >> 12, rr = r & 4095, o = rr >> 6, i = rr & 63;
  Wt[((size_t)half * 102400) + (k << 12) + (o << 6) + i] = f2bf(W[(k << 12) + (i << 6) + o]);
}

// ---------------- Y[n,k,o] via MFMA; LDS-staged full-line writeout; k+4 Wt prefetch ----------------
__global__ __launch_bounds__(256) void ygemm_kernel(
    const float* __restrict__ x, const unsigned short* __restrict__ Wt,
    unsigned short* __restrict__ Y) {
  __shared__ unsigned short tile[4][64 * 72];  // per-wave private, stride 144B
  const int n0 = blockIdx.x * 64;
  const int w = threadIdx.x >> 6;
  const int l = threadIdx.x & 63;
  const int lr = l & 15;
  const int lh = l >> 4;
  unsigned short* tl = tile[w];

  short8 bx[4][2];
  #pragma unroll
  for (int nt = 0; nt < 4; ++nt) {
    const float* xp = x + ((size_t)(n0 + nt * 16 + lr) << 6) + (lh << 3);
    #pragma unroll
    for (int h = 0; h < 2; ++h) {
      float4 lo = *(const float4*)(xp + h * 32);
      float4 hi = *(const float4*)(xp + h * 32 + 4);
      short8 b;
      b[0] = (short)f2bf(lo.x); b[1] = (short)f2bf(lo.y);
      b[2] = (short)f2bf(lo.z); b[3] = (short)f2bf(lo.w);
      b[4] = (short)f2bf(hi.x); b[5] = (short)f2bf(hi.y);
      b[6] = (short)f2bf(hi.z); b[7] = (short)f2bf(hi.w);
      bx[nt][h] = b;
    }
  }

  const f32x4 Z = {0.0f, 0.0f, 0.0f, 0.0f};

  int k = w;
  short8 aw[4][2];
  {
    const unsigned short* wk = Wt + ((size_t)k << 12);
    #pragma unroll
    for (int ot = 0; ot < 4; ++ot)
      #pragma unroll
      for (int h = 0; h < 2; ++h)
        aw[ot][h] = *(const short8*)(wk + ((ot * 16 + lr) << 6) + (h << 5) + (lh << 3));
  }

  while (k < 25) {
    const int kn = k + 4;
    short8 awn[4][2];
    if (kn < 25) {  // prefetch next-k fragments; overlaps MFMA + LDS phase below
      const unsigned short* wk = Wt + ((size_t)kn << 12);
      #pragma unroll
      for (int ot = 0; ot < 4; ++ot)
        #pragma unroll
        for (int h = 0; h < 2; ++h)
          awn[ot][h] = *(const short8*)(wk + ((ot * 16 + lr) << 6) + (h << 5) + (lh << 3));
    }

    f32x4 acc[4][4];
    #pragma unroll
    for (int ot = 0; ot < 4; ++ot)
      #pragma unroll
      for (int nt = 0; nt < 4; ++nt) {
        acc[ot][nt] = __builtin_amdgcn_mfma_f32_16x16x32_bf16(aw[ot][0], bx[nt][0], Z, 0, 0, 0);
        acc[ot][nt] = __builtin_amdgcn_mfma_f32_16x16x32_bf16(aw[ot][1], bx[nt][1], acc[ot][nt], 0, 0, 0);
      }

    #pragma unroll
    for (int ot = 0; ot < 4; ++ot)
      #pragma unroll
      for (int nt = 0; nt < 4; ++nt) {
        int node = nt * 16 + lr;
        int o = ot * 16 + (lh << 2);
        uint2 p;
        p.x = (unsigned)f2bf(acc[ot][nt][0]) | ((unsigned)f2bf(acc[ot][nt][1]) << 16);
        p.y = (unsigned)f2bf(acc[ot][nt][2]) | ((unsigned)f2bf(acc[ot][nt][3]) << 16);
        *(uint2*)(tl + node * 72 + o) = p;
      }

    #pragma unroll
    for (int r8 = 0; r8 < 8; ++r8) {
      int node = r8 * 8 + (l >> 3);
      int c = (l & 7) << 3;
      uint4 v = *(const uint4*)(tl + node * 72 + c);
      *(uint4*)(Y + ((size_t)(n0 + node) * 25 + k) * 64 + c) = v;
    }

    #pragma unroll
    for (int ot = 0; ot < 4; ++ot)
      #pragma unroll
      for (int h = 0; h < 2; ++h)
        aw[ot][h] = awn[ot][h];
    k = kn;
  }
}

// ---------------- CSR build: histogram -> 3-stage parallel scan -> scatter ----------------
__global__ __launch_bounds__(256) void hist_kernel(
    const int* __restrict__ ei, int* __restrict__ cnt) {
  int e = blockIdx.x * 256 + threadIdx.x;
  atomicAdd(&cnt[ei[E_N + e]], 1);
}

__global__ __launch_bounds__(256) void scan1_kernel(
    const int* __restrict__ cnt, int* __restrict__ bsum) {
  __shared__ int red[256];
  int t = threadIdx.x;
  int j = blockIdx.x * 256 + t;
  red[t] = (j < N_N) ? cnt[j] : 0;
  __syncthreads();
  #pragma unroll
  for (int s = 128; s > 0; s >>= 1) {
    if (t < s) red[t] += red[t + s];
    __syncthreads();
  }
  if (t == 0) bsum[blockIdx.x] = red[0];
}

__global__ __launch_bounds__(256) void scan2_kernel(
    const int* __restrict__ bsum, int* __restrict__ bofs) {
  __shared__ int v[256];
  int t = threadIdx.x;
  v[t] = (t < SCAN_B) ? bsum[t] : 0;
  __syncthreads();
  if (t == 0) {
    int acc = 0;
    for (int i = 0; i < SCAN_B; ++i) { int c = v[i]; v[i] = acc; acc += c; }
  }
  __syncthreads();
  if (t < SCAN_B) bofs[t] = v[t];
}

__global__ __launch_bounds__(256) void scan3_kernel(
    int* __restrict__ cnt, const int* __restrict__ bofs,
    int* __restrict__ start) {
  __shared__ int v[2][256];
  int t = threadIdx.x;
  int j = blockIdx.x * 256 + t;
  int c = (j < N_N) ? cnt[j] : 0;
  v[0][t] = c;
  __syncthreads();
  int cur = 0;
  #pragma unroll
  for (int s = 1; s < 256; s <<= 1) {
    v[1 - cur][t] = (t >= s) ? v[cur][t] + v[cur][t - s] : v[cur][t];
    __syncthreads();
    cur = 1 - cur;
  }
  if (j < N_N) {
    int ex = bofs[blockIdx.x] + v[cur][t] - c;
    start[j] = ex;
    cnt[j] = ex;  // becomes the scatter cursor
    if (j == 0) start[N_N] = E_N;
  }
}

// recs: uint2 { src | I0<<16, q0 | q1<<16 }  (q = 16-bit fixed-point frac)
__global__ __launch_bounds__(256) void scatter_kernel(
    const float* __restrict__ ea, const int* __restrict__ ei,
    int* __restrict__ ofs, uint2* __restrict__ recs) {
  int e = blockIdx.x * 256 + threadIdx.x;
  int s = ei[e];
  int d = ei[E_N + e];
  float2 a = ((const float2*)ea)[e];
  float v0 = a.x * 4.0f, v1 = a.y * 4.0f;
  float b0f = fminf(fmaxf(floorf(v0), 0.0f), 3.0f);
  float b1f = fminf(fmaxf(floorf(v1), 0.0f), 3.0f);
  float f0 = v0 - b0f, f1 = v1 - b1f;
  int I0 = (int)b0f * 5 + (int)b1f;
  unsigned int q0 = (unsigned int)(f0 * 65535.0f + 0.5f);
  unsigned int q1 = (unsigned int)(f1 * 65535.0f + 0.5f);
  int pos = atomicAdd(&ofs[d], 1);
  uint2 rc;
  rc.x = (unsigned int)s | ((unsigned int)I0 << 16);
  rc.y = q0 | (q1 << 16);
  recs[pos] = rc;
}

// ---------------- agg: persistent work-stealing waves, root in LDS, scalarized edges ----------------
static __device__ __forceinline__ float emsg(
    const unsigned short* __restrict__ Y, unsigned int rx, unsigned int ry, int lane) {
  int src = rx & 0xffff;
  int I0 = rx >> 16;
  float f0 = (float)(ry & 0xffff) * (1.0f / 65535.0f);
  float f1 = (float)(ry >> 16) * (1.0f / 65535.0f);
  const unsigned short* base = Y + (size_t)src * 1600 + I0 * 64 + lane;
  float y0 = bf2f(base[0]);
  float y1 = bf2f(base[64]);
  float y2 = bf2f(base[320]);
  float y3 = bf2f(base[384]);
  return (1.0f - f0) * ((1.0f - f1) * y0 + f1 * y1) +
         f0 * ((1.0f - f1) * y2 + f1 * y3);
}

__global__ __launch_bounds__(256, 8) void agg_kernel(
    const unsigned short* __restrict__ Y, const uint2* __restrict__ recs,
    const int* __restrict__ start, const float* __restrict__ xin,
    const float* __restrict__ root, const float* __restrict__ bias,
    float* __restrict__ outp, int relu, int* __restrict__ ctr) {
  __shared__ float rl[64 * 64];  // root, staged once per block
  __shared__ float xl[4][64];    // per-wave x-row slot
  const int w = threadIdx.x >> 6;
  const int lane = threadIdx.x & 63;
  #pragma unroll
  for (int r = 0; r < 16; ++r)
    rl[threadIdx.x + 256 * r] = root[threadIdx.x + 256 * r];
  const float bi = bias[lane];
  __syncthreads();

  for (;;) {
    int base = 0;
    if (lane == 0) base = atomicAdd(ctr, CHUNK);
    base = __shfl(base, 0);
    if (base >= N_N) break;
    const int lim = (base + CHUNK < N_N) ? base + CHUNK : N_N;
    for (int n = base; n < lim; ++n) {
      xl[w][lane] = xin[((size_t)n << 6) + lane];  // wave-private: no barrier
      const int s = __builtin_amdgcn_readfirstlane(start[n]);
      const int e = __builtin_amdgcn_readfirstlane(start[n + 1]);
      const float NI = -__builtin_inff();
      float a0 = NI, a1 = NI, a2 = NI, a3 = NI;
      int j = s;
      for (; j + 4 <= e; j += 4) {
        uint2 r0 = recs[j];
        uint2 r1 = recs[j + 1];
        uint2 r2 = recs[j + 2];
        uint2 r3 = recs[j + 3];
        unsigned x0 = __builtin_amdgcn_readfirstlane(r0.x), y0 = __builtin_amdgcn_readfirstlane(r0.y);
        unsigned x1 = __builtin_amdgcn_readfirstlane(r1.x), y1 = __builtin_amdgcn_readfirstlane(r1.y);
        unsigned x2 = __builtin_amdgcn_readfirstlane(r2.x), y2 = __builtin_amdgcn_readfirstlane(r2.y);
        unsigned x3 = __builtin_amdgcn_readfirstlane(r3.x), y3 = __builtin_amdgcn_readfirstlane(r3.y);
        float m0 = emsg(Y, x0, y0, lane);
        float m1 = emsg(Y, x1, y1, lane);
        float m2 = emsg(Y, x2, y2, lane);
        float m3 = emsg(Y, x3, y3, lane);
        a0 = fmaxf(a0, m0);
        a1 = fmaxf(a1, m1);
        a2 = fmaxf(a2, m2);
        a3 = fmaxf(a3, m3);
      }
      for (; j < e; ++j) {
        uint2 rc = recs[j];
        unsigned rx = __builtin_amdgcn_readfirstlane(rc.x);
        unsigned ry = __builtin_amdgcn_readfirstlane(rc.y);
        a0 = fmaxf(a0, emsg(Y, rx, ry, lane));
      }
      float acc = fmaxf(fmaxf(a0, a1), fmaxf(a2, a3));
      if (s == e) acc = 0.0f;

      float r = bi;
      #pragma unroll 8
      for (int i = 0; i < 64; ++i)
        r += xl[w][i] * rl[(i << 6) + lane];
      r += acc;
      if (relu) r = fmaxf(r, 0.0f);
      outp[((size_t)n << 6) + lane] = r;
    }
  }
}

extern "C" void kernel_launch(void* const* d_in, const int* in_sizes, int n_in,
                              void* d_out, int out_size, void* d_ws, size_t ws_size,
                              hipStream_t stream) {
  const float* x = (const float*)d_in[0];
  const int* ei = (const int*)d_in[1];
  const float* ea = (const float*)d_in[2];
  const float* W1 = (const float*)d_in[3];
  const float* root1 = (const float*)d_in[4];
  const float* bias1 = (const float*)d_in[5];
  const float* W2 = (const float*)d_in[6];
  const float* root2 = (const float*)d_in[7];
  const float* bias2 = (const float*)d_in[8];
  float* out = (float*)d_out;

  const size_t yB = (size_t)N_N * 1600 * 2;        // 128,000,000
  const size_t rB = (size_t)E_N * 8;               //   5,120,000
  const size_t sB = (size_t)(N_N + 2) * 4;         //     160,008
  const size_t cB = (size_t)N_N * 4;               //     160,000
  const size_t wB = (size_t)2 * 25 * 64 * 64 * 2;  //     409,600
  const size_t bB = (size_t)1024 * 2 + 64;
  if (ws_size < yB + rB + sB + cB + wB + bB) return;

  char* p = (char*)d_ws;
  unsigned short* Y = (unsigned short*)p; p += yB;
  uint2* recs = (uint2*)p;                p += rB;
  int* startA = (int*)p;                  p += sB;
  int* cnt = (int*)p;                     p += cB;   // doubles as scatter cursor
  unsigned short* Wt = (unsigned short*)p; p += wB;  // Wt1 | Wt2
  int* bsum = (int*)p;                    p += 1024;
  int* bofs = (int*)p;                    p += 1024;
  int* ctr = (int*)p;                     // 2 work-stealing counters

  float* h = out;  // layer-1 output lives in d_out; fully overwritten by layer 2
  unsigned short* Wt1 = Wt;
  unsigned short* Wt2 = Wt + (size_t)25 * 64 * 64;

  dim3 blk(256);

  // ---- CSR build (once, shared by both layers) + both weight transposes + ctr reset ----
  hipMemsetAsync(cnt, 0, cB, stream);
  wtrans_kernel<<<800, blk, 0, stream>>>(W1, W2, Wt, ctr);
  hist_kernel<<<E_N / 256, blk, 0, stream>>>(ei, cnt);
  scan1_kernel<<<SCAN_B, blk, 0, stream>>>(cnt, bsum);
  scan2_kernel<<<1, blk, 0, stream>>>(bsum, bofs);
  scan3_kernel<<<SCAN_B, blk, 0, stream>>>(cnt, bofs, startA);
  scatter_kernel<<<E_N / 256, blk, 0, stream>>>(ea, ei, cnt, recs);

  // ---- layer 1 ----
  ygemm_kernel<<<N_N / 64, blk, 0, stream>>>(x, Wt1, Y);
  agg_kernel<<<AGG_BLOCKS, blk, 0, stream>>>(Y, recs, startA, x, root1, bias1, h, 1, ctr);

  // ---- layer 2 ----
  ygemm_kernel<<<N_N / 64, blk, 0, stream>>>(h, Wt2, Y);
  agg_kernel<<<AGG_BLOCKS, blk, 0, stream>>>(Y, recs, startA, h, root2, bias2, out, 0, ctr + 1);
}

// Round 12
// 300.572 us; speedup vs baseline: 2.2374x; 2.2374x over previous
//
#include <hip/hip_runtime.h>
#include <hip/hip_bf16.h>

#define E_N 640000
#define N_N 40000
#define SCAN_B 157  // ceil(40000/256)

typedef __attribute__((ext_vector_type(8))) short short8;
typedef __attribute__((ext_vector_type(4))) float f32x4;

static __device__ __forceinline__ unsigned short f2bf(float f) {
  __hip_bfloat16 h = __float2bfloat16(f);
  unsigned short u;
  __builtin_memcpy(&u, &h, 2);
  return u;
}
static __device__ __forceinline__ float bf2f(unsigned short u) {
  return __uint_as_float(((unsigned int)u) << 16);
}

// ---------------- Wt[layer][k][o][i] = bf16(W[k][i][o]), both layers in one dispatch ----------------
__global__ __launch_bounds__(256) void wtrans_kernel(
    const float* __restrict__ W1, const float* __restrict__ W2,
    unsigned short* __restrict__ Wt) {  // Wt: [2][25][64][64]
  int t = blockIdx.x * 256 + threadIdx.x;  // 0..204799
  int half = t >= 102400;
  int r = t - (half ? 102400 : 0);
  const float* W = half ? W2 : W1;
  int k = r >> 12, rr = r & 4095, o = rr >> 6, i = rr & 63;
  Wt[((size_t)half * 102400) + (k << 12) + (o << 6) + i] = f2bf(W[(k << 12) + (i << 6) + o]);
}

// ---------------- Y[n,k,o] via MFMA; one k per wave, grid (625, 7) ----------------
// LDS-staged full-line writeout (kills L2 write-allocate RMW of Y).
__global__ __launch_bounds__(256) void ygemm_kernel(
    const float* __restrict__ x, const unsigned short* __restrict__ Wt,
    unsigned short* __restrict__ Y) {
  __shared__ unsigned short tile[4][64 * 72];  // per-wave private, stride 144B
  const int n0 = blockIdx.x * 64;
  const int w = threadIdx.x >> 6;
  const int k = blockIdx.y * 4 + w;
  if (k >= 25) return;  // no block-wide barriers in this kernel; safe
  const int l = threadIdx.x & 63;
  const int lr = l & 15;
  const int lh = l >> 4;
  unsigned short* tl = tile[w];

  short8 bx[4][2];
  #pragma unroll
  for (int nt = 0; nt < 4; ++nt) {
    const float* xp = x + ((size_t)(n0 + nt * 16 + lr) << 6) + (lh << 3);
    #pragma unroll
    for (int h = 0; h < 2; ++h) {
      float4 lo = *(const float4*)(xp + h * 32);
      float4 hi = *(const float4*)(xp + h * 32 + 4);
      short8 b;
      b[0] = (short)f2bf(lo.x); b[1] = (short)f2bf(lo.y);
      b[2] = (short)f2bf(lo.z); b[3] = (short)f2bf(lo.w);
      b[4] = (short)f2bf(hi.x); b[5] = (short)f2bf(hi.y);
      b[6] = (short)f2bf(hi.z); b[7] = (short)f2bf(hi.w);
      bx[nt][h] = b;
    }
  }

  const unsigned short* wk = Wt + ((size_t)k << 12);
  short8 aw[4][2];
  #pragma unroll
  for (int ot = 0; ot < 4; ++ot)
    #pragma unroll
    for (int h = 0; h < 2; ++h)
      aw[ot][h] = *(const short8*)(wk + ((ot * 16 + lr) << 6) + (h << 5) + (lh << 3));

  const f32x4 Z = {0.0f, 0.0f, 0.0f, 0.0f};
  f32x4 acc[4][4];
  #pragma unroll
  for (int ot = 0; ot < 4; ++ot)
    #pragma unroll
    for (int nt = 0; nt < 4; ++nt) {
      acc[ot][nt] = __builtin_amdgcn_mfma_f32_16x16x32_bf16(aw[ot][0], bx[nt][0], Z, 0, 0, 0);
      acc[ot][nt] = __builtin_amdgcn_mfma_f32_16x16x32_bf16(aw[ot][1], bx[nt][1], acc[ot][nt], 0, 0, 0);
    }

  // pack C into per-wave LDS tile [node][o], row stride 72 shorts
  #pragma unroll
  for (int ot = 0; ot < 4; ++ot)
    #pragma unroll
    for (int nt = 0; nt < 4; ++nt) {
      int node = nt * 16 + lr;
      int o = ot * 16 + (lh << 2);
      uint2 p;
      p.x = (unsigned)f2bf(acc[ot][nt][0]) | ((unsigned)f2bf(acc[ot][nt][1]) << 16);
      p.y = (unsigned)f2bf(acc[ot][nt][2]) | ((unsigned)f2bf(acc[ot][nt][3]) << 16);
      *(uint2*)(tl + node * 72 + o) = p;
    }

  // copy out: each instruction writes 8 complete 128B lines
  #pragma unroll
  for (int r8 = 0; r8 < 8; ++r8) {
    int node = r8 * 8 + (l >> 3);
    int c = (l & 7) << 3;
    uint4 v = *(const uint4*)(tl + node * 72 + c);
    *(uint4*)(Y + ((size_t)(n0 + node) * 25 + k) * 64 + c) = v;
  }
}

// ---------------- CSR build: histogram -> 3-stage parallel scan -> scatter ----------------
__global__ __launch_bounds__(256) void hist_kernel(
    const int* __restrict__ ei, int* __restrict__ cnt) {
  int e = blockIdx.x * 256 + threadIdx.x;
  atomicAdd(&cnt[ei[E_N + e]], 1);
}

__global__ __launch_bounds__(256) void scan1_kernel(
    const int* __restrict__ cnt, int* __restrict__ bsum) {
  __shared__ int red[256];
  int t = threadIdx.x;
  int j = blockIdx.x * 256 + t;
  red[t] = (j < N_N) ? cnt[j] : 0;
  __syncthreads();
  #pragma unroll
  for (int s = 128; s > 0; s >>= 1) {
    if (t < s) red[t] += red[t + s];
    __syncthreads();
  }
  if (t == 0) bsum[blockIdx.x] = red[0];
}

__global__ __launch_bounds__(256) void scan2_kernel(
    const int* __restrict__ bsum, int* __restrict__ bofs) {
  __shared__ int v[256];
  int t = threadIdx.x;
  v[t] = (t < SCAN_B) ? bsum[t] : 0;
  __syncthreads();
  if (t == 0) {
    int acc = 0;
    for (int i = 0; i < SCAN_B; ++i) { int c = v[i]; v[i] = acc; acc += c; }
  }
  __syncthreads();
  if (t < SCAN_B) bofs[t] = v[t];
}

__global__ __launch_bounds__(256) void scan3_kernel(
    int* __restrict__ cnt, const int* __restrict__ bofs,
    int* __restrict__ start) {
  __shared__ int v[2][256];
  int t = threadIdx.x;
  int j = blockIdx.x * 256 + t;
  int c = (j < N_N) ? cnt[j] : 0;
  v[0][t] = c;
  __syncthreads();
  int cur = 0;
  #pragma unroll
  for (int s = 1; s < 256; s <<= 1) {
    v[1 - cur][t] = (t >= s) ? v[cur][t] + v[cur][t - s] : v[cur][t];
    __syncthreads();
    cur = 1 - cur;
  }
  if (j < N_N) {
    int ex = bofs[blockIdx.x] + v[cur][t] - c;
    start[j] = ex;
    cnt[j] = ex;  // becomes the scatter cursor
    if (j == 0) start[N_N] = E_N;
  }
}

// recs: uint2 { src | I0<<16, q0 | q1<<16 }  (q = 16-bit fixed-point frac)
__global__ __launch_bounds__(256) void scatter_kernel(
    const float* __restrict__ ea, const int* __restrict__ ei,
    int* __restrict__ ofs, uint2* __restrict__ recs) {
  int e = blockIdx.x * 256 + threadIdx.x;
  int s = ei[e];
  int d = ei[E_N + e];
  float2 a = ((const float2*)ea)[e];
  float v0 = a.x * 4.0f, v1 = a.y * 4.0f;
  float b0f = fminf(fmaxf(floorf(v0), 0.0f), 3.0f);
  float b1f = fminf(fmaxf(floorf(v1), 0.0f), 3.0f);
  float f0 = v0 - b0f, f1 = v1 - b1f;
  int I0 = (int)b0f * 5 + (int)b1f;
  unsigned int q0 = (unsigned int)(f0 * 65535.0f + 0.5f);
  unsigned int q1 = (unsigned int)(f1 * 65535.0f + 0.5f);
  int pos = atomicAdd(&ofs[d], 1);
  uint2 rc;
  rc.x = (unsigned int)s | ((unsigned int)I0 << 16);
  rc.y = q0 | (q1 << 16);
  recs[pos] = rc;
}

// ---------------- agg (one wave per dst node, 4 indep max chains, scalarized) ----------------
static __device__ __forceinline__ float emsg(
    const unsigned short* __restrict__ Y, unsigned int rx, unsigned int ry, int lane) {
  // rx, ry are wave-uniform (readfirstlane'd) -> address math on SALU
  int src = rx & 0xffff;
  int I0 = rx >> 16;
  float f0 = (float)(ry & 0xffff) * (1.0f / 65535.0f);
  float f1 = (float)(ry >> 16) * (1.0f / 65535.0f);
  const unsigned short* base = Y + (size_t)src * 1600 + I0 * 64 + lane;
  float y0 = bf2f(base[0]);
  float y1 = bf2f(base[64]);
  float y2 = bf2f(base[320]);
  float y3 = bf2f(base[384]);
  return (1.0f - f0) * ((1.0f - f1) * y0 + f1 * y1) +
         f0 * ((1.0f - f1) * y2 + f1 * y3);
}

__global__ __launch_bounds__(256) void agg_kernel(
    const unsigned short* __restrict__ Y, const uint2* __restrict__ recs,
    const int* __restrict__ start, const float* __restrict__ xin,
    const float* __restrict__ root, const float* __restrict__ bias,
    float* __restrict__ outp, int relu) {
  __shared__ float xl[4][64];
  const int w = threadIdx.x >> 6;
  const int lane = threadIdx.x & 63;
  const int n = blockIdx.x * 4 + w;
  xl[w][lane] = xin[((size_t)n << 6) + lane];
  __syncthreads();

  const int s = __builtin_amdgcn_readfirstlane(start[n]);
  const int e = __builtin_amdgcn_readfirstlane(start[n + 1]);
  const float NI = -__builtin_inff();
  float a0 = NI, a1 = NI, a2 = NI, a3 = NI;
  int j = s;
  for (; j + 4 <= e; j += 4) {
    uint2 r0 = recs[j];
    uint2 r1 = recs[j + 1];
    uint2 r2 = recs[j + 2];
    uint2 r3 = recs[j + 3];
    unsigned x0 = __builtin_amdgcn_readfirstlane(r0.x), y0 = __builtin_amdgcn_readfirstlane(r0.y);
    unsigned x1 = __builtin_amdgcn_readfirstlane(r1.x), y1 = __builtin_amdgcn_readfirstlane(r1.y);
    unsigned x2 = __builtin_amdgcn_readfirstlane(r2.x), y2 = __builtin_amdgcn_readfirstlane(r2.y);
    unsigned x3 = __builtin_amdgcn_readfirstlane(r3.x), y3 = __builtin_amdgcn_readfirstlane(r3.y);
    float m0 = emsg(Y, x0, y0, lane);
    float m1 = emsg(Y, x1, y1, lane);
    float m2 = emsg(Y, x2, y2, lane);
    float m3 = emsg(Y, x3, y3, lane);
    a0 = fmaxf(a0, m0);
    a1 = fmaxf(a1, m1);
    a2 = fmaxf(a2, m2);
    a3 = fmaxf(a3, m3);
  }
  for (; j < e; ++j) {
    uint2 rc = recs[j];
    unsigned rx = __builtin_amdgcn_readfirstlane(rc.x);
    unsigned ry = __builtin_amdgcn_readfirstlane(rc.y);
    a0 = fmaxf(a0, emsg(Y, rx, ry, lane));
  }
  float acc = fmaxf(fmaxf(a0, a1), fmaxf(a2, a3));
  if (s == e) acc = 0.0f;

  float r = bias[lane];
  #pragma unroll 8
  for (int i = 0; i < 64; ++i)
    r += xl[w][i] * root[(i << 6) + lane];
  r += acc;
  if (relu) r = fmaxf(r, 0.0f);
  outp[((size_t)n << 6) + lane] = r;
}

extern "C" void kernel_launch(void* const* d_in, const int* in_sizes, int n_in,
                              void* d_out, int out_size, void* d_ws, size_t ws_size,
                              hipStream_t stream) {
  const float* x = (const float*)d_in[0];
  const int* ei = (const int*)d_in[1];
  const float* ea = (const float*)d_in[2];
  const float* W1 = (const float*)d_in[3];
  const float* root1 = (const float*)d_in[4];
  const float* bias1 = (const float*)d_in[5];
  const float* W2 = (const float*)d_in[6];
  const float* root2 = (const float*)d_in[7];
  const float* bias2 = (const float*)d_in[8];
  float* out = (float*)d_out;

  const size_t yB = (size_t)N_N * 1600 * 2;        // 128,000,000
  const size_t rB = (size_t)E_N * 8;               //   5,120,000
  const size_t sB = (size_t)(N_N + 2) * 4;         //     160,008
  const size_t cB = (size_t)N_N * 4;               //     160,000
  const size_t wB = (size_t)2 * 25 * 64 * 64 * 2;  //     409,600
  const size_t bB = (size_t)1024 * 2;
  if (ws_size < yB + rB + sB + cB + wB + bB) return;

  char* p = (char*)d_ws;
  unsigned short* Y = (unsigned short*)p; p += yB;
  uint2* recs = (uint2*)p;                p += rB;
  int* startA = (int*)p;                  p += sB;
  int* cnt = (int*)p;                     p += cB;   // doubles as scatter cursor
  unsigned short* Wt = (unsigned short*)p; p += wB;  // Wt1 | Wt2
  int* bsum = (int*)p;                    p += 1024;
  int* bofs = (int*)p;
  float* h = out;  // layer-1 output lives in d_out; fully overwritten by layer 2

  unsigned short* Wt1 = Wt;
  unsigned short* Wt2 = Wt + (size_t)25 * 64 * 64;

  dim3 blk(256);

  // ---- CSR build (once, shared by both layers) + both weight transposes ----
  hipMemsetAsync(cnt, 0, cB, stream);
  wtrans_kernel<<<800, blk, 0, stream>>>(W1, W2, Wt);
  hist_kernel<<<E_N / 256, blk, 0, stream>>>(ei, cnt);
  scan1_kernel<<<SCAN_B, blk, 0, stream>>>(cnt, bsum);
  scan2_kernel<<<1, blk, 0, stream>>>(bsum, bofs);
  scan3_kernel<<<SCAN_B, blk, 0, stream>>>(cnt, bofs, startA);
  scatter_kernel<<<E_N / 256, blk, 0, stream>>>(ea, ei, cnt, recs);

  // ---- layer 1 ----
  ygemm_kernel<<<dim3(N_N / 64, 7), blk, 0, stream>>>(x, Wt1, Y);
  agg_kernel<<<N_N / 4, blk, 0, stream>>>(Y, recs, startA, x, root1, bias1, h, 1);

  // ---- layer 2 ----
  ygemm_kernel<<<dim3(N_N / 64, 7), blk, 0, stream>>>(h, Wt2, Y);
  agg_kernel<<<N_N / 4, blk, 0, stream>>>(Y, recs, startA, h, root2, bias2, out, 0);
}

// Round 13
// 275.088 us; speedup vs baseline: 2.4446x; 1.0926x over previous
//
#include <hip/hip_runtime.h>
#include <hip/hip_bf16.h>

#define E_N 640000
#define N_N 40000
#define SCAN_B 157  // ceil(40000/256)

typedef __attribute__((ext_vector_type(8))) short short8;
typedef __attribute__((ext_vector_type(4))) float f32x4;

static __device__ __forceinline__ unsigned short f2bf(float f) {
  __hip_bfloat16 h = __float2bfloat16(f);
  unsigned short u;
  __builtin_memcpy(&u, &h, 2);
  return u;
}
static __device__ __forceinline__ float bf2f(unsigned short u) {
  return __uint_as_float(((unsigned int)u) << 16);
}

// ---------------- Wt[layer][k][o][i] = bf16(W[k][i][o]); blocks 0..156 also zero cnt ----------------
__global__ __launch_bounds__(256) void wtrans_kernel(
    const float* __restrict__ W1, const float* __restrict__ W2,
    unsigned short* __restrict__ Wt, int* __restrict__ cnt) {
  if (blockIdx.x < SCAN_B) {
    int j = blockIdx.x * 256 + threadIdx.x;
    if (j < N_N) cnt[j] = 0;
  }
  int t = blockIdx.x * 256 + threadIdx.x;  // 0..204799
  int half = t >= 102400;
  int r = t - (half ? 102400 : 0);
  const float* W = half ? W2 : W1;
  int k = r >> 12, rr = r & 4095, o = rr >> 6, i = rr & 63;
  Wt[((size_t)half * 102400) + (k << 12) + (o << 6) + i] = f2bf(W[(k << 12) + (i << 6) + o]);
}

// ---------------- Y[n,k,o] via MFMA; 32-node tiles, per-wave k-loop + prefetch ----------------
// LDS-staged full-line writeout (kills L2 write-allocate RMW of Y).
__global__ __launch_bounds__(256) void ygemm_kernel(
    const float* __restrict__ x, const unsigned short* __restrict__ Wt,
    unsigned short* __restrict__ Y) {
  __shared__ unsigned short tile[4][32 * 72];  // per-wave private, stride 144B
  const int n0 = blockIdx.x * 32;
  const int w = threadIdx.x >> 6;
  const int l = threadIdx.x & 63;
  const int lr = l & 15;
  const int lh = l >> 4;
  unsigned short* tl = tile[w];

  short8 bx[2][2];
  #pragma unroll
  for (int nt = 0; nt < 2; ++nt) {
    const float* xp = x + ((size_t)(n0 + nt * 16 + lr) << 6) + (lh << 3);
    #pragma unroll
    for (int h = 0; h < 2; ++h) {
      float4 lo = *(const float4*)(xp + h * 32);
      float4 hi = *(const float4*)(xp + h * 32 + 4);
      short8 b;
      b[0] = (short)f2bf(lo.x); b[1] = (short)f2bf(lo.y);
      b[2] = (short)f2bf(lo.z); b[3] = (short)f2bf(lo.w);
      b[4] = (short)f2bf(hi.x); b[5] = (short)f2bf(hi.y);
      b[6] = (short)f2bf(hi.z); b[7] = (short)f2bf(hi.w);
      bx[nt][h] = b;
    }
  }

  const f32x4 Z = {0.0f, 0.0f, 0.0f, 0.0f};

  int k = w;
  short8 aw[4][2];
  {
    const unsigned short* wk = Wt + ((size_t)k << 12);
    #pragma unroll
    for (int ot = 0; ot < 4; ++ot)
      #pragma unroll
      for (int h = 0; h < 2; ++h)
        aw[ot][h] = *(const short8*)(wk + ((ot * 16 + lr) << 6) + (h << 5) + (lh << 3));
  }

  while (k < 25) {
    const int kn = k + 4;
    short8 awn[4][2];
    if (kn < 25) {  // prefetch next-k fragments; overlaps MFMA + LDS phase below
      const unsigned short* wk = Wt + ((size_t)kn << 12);
      #pragma unroll
      for (int ot = 0; ot < 4; ++ot)
        #pragma unroll
        for (int h = 0; h < 2; ++h)
          awn[ot][h] = *(const short8*)(wk + ((ot * 16 + lr) << 6) + (h << 5) + (lh << 3));
    }

    f32x4 acc[4][2];
    #pragma unroll
    for (int ot = 0; ot < 4; ++ot)
      #pragma unroll
      for (int nt = 0; nt < 2; ++nt) {
        acc[ot][nt] = __builtin_amdgcn_mfma_f32_16x16x32_bf16(aw[ot][0], bx[nt][0], Z, 0, 0, 0);
        acc[ot][nt] = __builtin_amdgcn_mfma_f32_16x16x32_bf16(aw[ot][1], bx[nt][1], acc[ot][nt], 0, 0, 0);
      }

    // pack C into per-wave LDS tile [node][o], row stride 72 shorts
    #pragma unroll
    for (int ot = 0; ot < 4; ++ot)
      #pragma unroll
      for (int nt = 0; nt < 2; ++nt) {
        int node = nt * 16 + lr;
        int o = ot * 16 + (lh << 2);
        uint2 p;
        p.x = (unsigned)f2bf(acc[ot][nt][0]) | ((unsigned)f2bf(acc[ot][nt][1]) << 16);
        p.y = (unsigned)f2bf(acc[ot][nt][2]) | ((unsigned)f2bf(acc[ot][nt][3]) << 16);
        *(uint2*)(tl + node * 72 + o) = p;
      }

    // copy out: each instruction writes 8 complete 128B lines
    #pragma unroll
    for (int r8 = 0; r8 < 4; ++r8) {
      int node = r8 * 8 + (l >> 3);
      int c = (l & 7) << 3;
      uint4 v = *(const uint4*)(tl + node * 72 + c);
      *(uint4*)(Y + ((size_t)(n0 + node) * 25 + k) * 64 + c) = v;
    }

    #pragma unroll
    for (int ot = 0; ot < 4; ++ot)
      #pragma unroll
      for (int h = 0; h < 2; ++h)
        aw[ot][h] = awn[ot][h];
    k = kn;
  }
}

// ---------------- CSR build: histogram -> 3-stage parallel scan -> scatter ----------------
__global__ __launch_bounds__(256) void hist_kernel(
    const int* __restrict__ ei, int* __restrict__ cnt) {
  int e = blockIdx.x * 256 + threadIdx.x;
  atomicAdd(&cnt[ei[E_N + e]], 1);
}

__global__ __launch_bounds__(256) void scan1_kernel(
    const int* __restrict__ cnt, int* __restrict__ bsum) {
  __shared__ int red[256];
  int t = threadIdx.x;
  int j = blockIdx.x * 256 + t;
  red[t] = (j < N_N) ? cnt[j] : 0;
  __syncthreads();
  #pragma unroll
  for (int s = 128; s > 0; s >>= 1) {
    if (t < s) red[t] += red[t + s];
    __syncthreads();
  }
  if (t == 0) bsum[blockIdx.x] = red[0];
}

__global__ __launch_bounds__(256) void scan2_kernel(
    const int* __restrict__ bsum, int* __restrict__ bofs) {
  __shared__ int v[256];
  int t = threadIdx.x;
  v[t] = (t < SCAN_B) ? bsum[t] : 0;
  __syncthreads();
  if (t == 0) {
    int acc = 0;
    for (int i = 0; i < SCAN_B; ++i) { int c = v[i]; v[i] = acc; acc += c; }
  }
  __syncthreads();
  if (t < SCAN_B) bofs[t] = v[t];
}

__global__ __launch_bounds__(256) void scan3_kernel(
    int* __restrict__ cnt, const int* __restrict__ bofs,
    int* __restrict__ start) {
  __shared__ int v[2][256];
  int t = threadIdx.x;
  int j = blockIdx.x * 256 + t;
  int c = (j < N_N) ? cnt[j] : 0;
  v[0][t] = c;
  __syncthreads();
  int cur = 0;
  #pragma unroll
  for (int s = 1; s < 256; s <<= 1) {
    v[1 - cur][t] = (t >= s) ? v[cur][t] + v[cur][t - s] : v[cur][t];
    __syncthreads();
    cur = 1 - cur;
  }
  if (j < N_N) {
    int ex = bofs[blockIdx.x] + v[cur][t] - c;
    start[j] = ex;
    cnt[j] = ex;  // becomes the scatter cursor
    if (j == 0) start[N_N] = E_N;
  }
}

// recs: uint2 { src | I0<<16, q0 | q1<<16 }  (q = 16-bit fixed-point frac)
__global__ __launch_bounds__(256) void scatter_kernel(
    const float* __restrict__ ea, const int* __restrict__ ei,
    int* __restrict__ ofs, uint2* __restrict__ recs) {
  int e = blockIdx.x * 256 + threadIdx.x;
  int s = ei[e];
  int d = ei[E_N + e];
  float2 a = ((const float2*)ea)[e];
  float v0 = a.x * 4.0f, v1 = a.y * 4.0f;
  float b0f = fminf(fmaxf(floorf(v0), 0.0f), 3.0f);
  float b1f = fminf(fmaxf(floorf(v1), 0.0f), 3.0f);
  float f0 = v0 - b0f, f1 = v1 - b1f;
  int I0 = (int)b0f * 5 + (int)b1f;
  unsigned int q0 = (unsigned int)(f0 * 65535.0f + 0.5f);
  unsigned int q1 = (unsigned int)(f1 * 65535.0f + 0.5f);
  int pos = atomicAdd(&ofs[d], 1);
  uint2 rc;
  rc.x = (unsigned int)s | ((unsigned int)I0 << 16);
  rc.y = q0 | (q1 << 16);
  recs[pos] = rc;
}

// ---------------- agg (one wave per dst node, 4 indep max chains, scalarized) ----------------
static __device__ __forceinline__ float emsg(
    const unsigned short* __restrict__ Y, unsigned int rx, unsigned int ry, int lane) {
  // rx, ry are wave-uniform (readfirstlane'd) -> address math on SALU
  int src = rx & 0xffff;
  int I0 = rx >> 16;
  float f0 = (float)(ry & 0xffff) * (1.0f / 65535.0f);
  float f1 = (float)(ry >> 16) * (1.0f / 65535.0f);
  const unsigned short* base = Y + (size_t)src * 1600 + I0 * 64 + lane;
  float y0 = bf2f(base[0]);
  float y1 = bf2f(base[64]);
  float y2 = bf2f(base[320]);
  float y3 = bf2f(base[384]);
  return (1.0f - f0) * ((1.0f - f1) * y0 + f1 * y1) +
         f0 * ((1.0f - f1) * y2 + f1 * y3);
}

__global__ __launch_bounds__(256) void agg_kernel(
    const unsigned short* __restrict__ Y, const uint2* __restrict__ recs,
    const int* __restrict__ start, const float* __restrict__ xin,
    const float* __restrict__ root, const float* __restrict__ bias,
    float* __restrict__ outp, int relu) {
  __shared__ float xl[4][64];
  const int w = threadIdx.x >> 6;
  const int lane = threadIdx.x & 63;
  const int n = blockIdx.x * 4 + w;
  xl[w][lane] = xin[((size_t)n << 6) + lane];
  __syncthreads();

  const int s = __builtin_amdgcn_readfirstlane(start[n]);
  const int e = __builtin_amdgcn_readfirstlane(start[n + 1]);
  const float NI = -__builtin_inff();
  float a0 = NI, a1 = NI, a2 = NI, a3 = NI;
  int j = s;
  for (; j + 4 <= e; j += 4) {
    uint2 r0 = recs[j];
    uint2 r1 = recs[j + 1];
    uint2 r2 = recs[j + 2];
    uint2 r3 = recs[j + 3];
    unsigned x0 = __builtin_amdgcn_readfirstlane(r0.x), y0 = __builtin_amdgcn_readfirstlane(r0.y);
    unsigned x1 = __builtin_amdgcn_readfirstlane(r1.x), y1 = __builtin_amdgcn_readfirstlane(r1.y);
    unsigned x2 = __builtin_amdgcn_readfirstlane(r2.x), y2 = __builtin_amdgcn_readfirstlane(r2.y);
    unsigned x3 = __builtin_amdgcn_readfirstlane(r3.x), y3 = __builtin_amdgcn_readfirstlane(r3.y);
    float m0 = emsg(Y, x0, y0, lane);
    float m1 = emsg(Y, x1, y1, lane);
    float m2 = emsg(Y, x2, y2, lane);
    float m3 = emsg(Y, x3, y3, lane);
    a0 = fmaxf(a0, m0);
    a1 = fmaxf(a1, m1);
    a2 = fmaxf(a2, m2);
    a3 = fmaxf(a3, m3);
  }
  for (; j < e; ++j) {
    uint2 rc = recs[j];
    unsigned rx = __builtin_amdgcn_readfirstlane(rc.x);
    unsigned ry = __builtin_amdgcn_readfirstlane(rc.y);
    a0 = fmaxf(a0, emsg(Y, rx, ry, lane));
  }
  float acc = fmaxf(fmaxf(a0, a1), fmaxf(a2, a3));
  if (s == e) acc = 0.0f;

  float r = bias[lane];
  #pragma unroll 8
  for (int i = 0; i < 64; ++i)
    r += xl[w][i] * root[(i << 6) + lane];
  r += acc;
  if (relu) r = fmaxf(r, 0.0f);
  outp[((size_t)n << 6) + lane] = r;
}

extern "C" void kernel_launch(void* const* d_in, const int* in_sizes, int n_in,
                              void* d_out, int out_size, void* d_ws, size_t ws_size,
                              hipStream_t stream) {
  const float* x = (const float*)d_in[0];
  const int* ei = (const int*)d_in[1];
  const float* ea = (const float*)d_in[2];
  const float* W1 = (const float*)d_in[3];
  const float* root1 = (const float*)d_in[4];
  const float* bias1 = (const float*)d_in[5];
  const float* W2 = (const float*)d_in[6];
  const float* root2 = (const float*)d_in[7];
  const float* bias2 = (const float*)d_in[8];
  float* out = (float*)d_out;

  const size_t yB = (size_t)N_N * 1600 * 2;        // 128,000,000
  const size_t rB = (size_t)E_N * 8;               //   5,120,000
  const size_t sB = (size_t)(N_N + 2) * 4;         //     160,008
  const size_t cB = (size_t)N_N * 4;               //     160,000
  const size_t wB = (size_t)2 * 25 * 64 * 64 * 2;  //     409,600
  const size_t bB = (size_t)1024 * 2;
  if (ws_size < yB + rB + sB + cB + wB + bB) return;

  char* p = (char*)d_ws;
  unsigned short* Y = (unsigned short*)p; p += yB;
  uint2* recs = (uint2*)p;                p += rB;
  int* startA = (int*)p;                  p += sB;
  int* cnt = (int*)p;                     p += cB;   // doubles as scatter cursor
  unsigned short* Wt = (unsigned short*)p; p += wB;  // Wt1 | Wt2
  int* bsum = (int*)p;                    p += 1024;
  int* bofs = (int*)p;
  float* h = out;  // layer-1 output lives in d_out; fully overwritten by layer 2

  unsigned short* Wt1 = Wt;
  unsigned short* Wt2 = Wt + (size_t)25 * 64 * 64;

  dim3 blk(256);

  // ---- CSR build (once, shared by both layers) + weight transposes (also zeroes cnt) ----
  wtrans_kernel<<<800, blk, 0, stream>>>(W1, W2, Wt, cnt);
  hist_kernel<<<E_N / 256, blk, 0, stream>>>(ei, cnt);
  scan1_kernel<<<SCAN_B, blk, 0, stream>>>(cnt, bsum);
  scan2_kernel<<<1, blk, 0, stream>>>(bsum, bofs);
  scan3_kernel<<<SCAN_B, blk, 0, stream>>>(cnt, bofs, startA);
  scatter_kernel<<<E_N / 256, blk, 0, stream>>>(ea, ei, cnt, recs);

  // ---- layer 1 ----
  ygemm_kernel<<<N_N / 32, blk, 0, stream>>>(x, Wt1, Y);
  agg_kernel<<<N_N / 4, blk, 0, stream>>>(Y, recs, startA, x, root1, bias1, h, 1);

  // ---- layer 2 ----
  ygemm_kernel<<<N_N / 32, blk, 0, stream>>>(h, Wt2, Y);
  agg_kernel<<<N_N / 4, blk, 0, stream>>>(Y, recs, startA, h, root2, bias2, out, 0);
}

// Round 14
// 260.749 us; speedup vs baseline: 2.5791x; 1.0550x over previous
//
#include <hip/hip_runtime.h>
#include <hip/hip_bf16.h>

#define E_N 640000
#define N_N 40000
#define SCAN_B 157  // ceil(40000/256)

typedef __attribute__((ext_vector_type(8))) short short8;
typedef __attribute__((ext_vector_type(4))) float f32x4;

static __device__ __forceinline__ unsigned short f2bf(float f) {
  __hip_bfloat16 h = __float2bfloat16(f);
  unsigned short u;
  __builtin_memcpy(&u, &h, 2);
  return u;
}
static __device__ __forceinline__ float bf2f(unsigned short u) {
  return __uint_as_float(((unsigned int)u) << 16);
}

// ---------------- Wt[layer][k][o][i] = bf16(W[k][i][o]); blocks 0..156 also zero cnt ----------------
__global__ __launch_bounds__(256) void wtrans_kernel(
    const float* __restrict__ W1, const float* __restrict__ W2,
    unsigned short* __restrict__ Wt, int* __restrict__ cnt) {
  if (blockIdx.x < SCAN_B) {
    int j = blockIdx.x * 256 + threadIdx.x;
    if (j < N_N) cnt[j] = 0;
  }
  int t = blockIdx.x * 256 + threadIdx.x;  // 0..204799
  int half = t >= 102400;
  int r = t - (half ? 102400 : 0);
  const float* W = half ? W2 : W1;
  int k = r >> 12, rr = r & 4095, o = rr >> 6, i = rr & 63;
  Wt[((size_t)half * 102400) + (k << 12) + (o << 6) + i] = f2bf(W[(k << 12) + (i << 6) + o]);
}

// ---------------- Y[n,k,o] via MFMA; 64-node tiles, per-wave k-loop + k+4 prefetch ----------------
// LDS-staged full-line writeout (kills L2 write-allocate RMW of Y).  [R9 proven form]
__global__ __launch_bounds__(256) void ygemm_kernel(
    const float* __restrict__ x, const unsigned short* __restrict__ Wt,
    unsigned short* __restrict__ Y) {
  __shared__ unsigned short tile[4][64 * 72];  // per-wave private, stride 144B
  const int n0 = blockIdx.x * 64;
  const int w = threadIdx.x >> 6;
  const int l = threadIdx.x & 63;
  const int lr = l & 15;
  const int lh = l >> 4;
  unsigned short* tl = tile[w];

  short8 bx[4][2];
  #pragma unroll
  for (int nt = 0; nt < 4; ++nt) {
    const float* xp = x + ((size_t)(n0 + nt * 16 + lr) << 6) + (lh << 3);
    #pragma unroll
    for (int h = 0; h < 2; ++h) {
      float4 lo = *(const float4*)(xp + h * 32);
      float4 hi = *(const float4*)(xp + h * 32 + 4);
      short8 b;
      b[0] = (short)f2bf(lo.x); b[1] = (short)f2bf(lo.y);
      b[2] = (short)f2bf(lo.z); b[3] = (short)f2bf(lo.w);
      b[4] = (short)f2bf(hi.x); b[5] = (short)f2bf(hi.y);
      b[6] = (short)f2bf(hi.z); b[7] = (short)f2bf(hi.w);
      bx[nt][h] = b;
    }
  }

  const f32x4 Z = {0.0f, 0.0f, 0.0f, 0.0f};

  int k = w;
  short8 aw[4][2];
  {
    const unsigned short* wk = Wt + ((size_t)k << 12);
    #pragma unroll
    for (int ot = 0; ot < 4; ++ot)
      #pragma unroll
      for (int h = 0; h < 2; ++h)
        aw[ot][h] = *(const short8*)(wk + ((ot * 16 + lr) << 6) + (h << 5) + (lh << 3));
  }

  while (k < 25) {
    const int kn = k + 4;
    short8 awn[4][2];
    if (kn < 25) {  // prefetch next-k fragments; overlaps MFMA + LDS phase below
      const unsigned short* wk = Wt + ((size_t)kn << 12);
      #pragma unroll
      for (int ot = 0; ot < 4; ++ot)
        #pragma unroll
        for (int h = 0; h < 2; ++h)
          awn[ot][h] = *(const short8*)(wk + ((ot * 16 + lr) << 6) + (h << 5) + (lh << 3));
    }

    f32x4 acc[4][4];
    #pragma unroll
    for (int ot = 0; ot < 4; ++ot)
      #pragma unroll
      for (int nt = 0; nt < 4; ++nt) {
        acc[ot][nt] = __builtin_amdgcn_mfma_f32_16x16x32_bf16(aw[ot][0], bx[nt][0], Z, 0, 0, 0);
        acc[ot][nt] = __builtin_amdgcn_mfma_f32_16x16x32_bf16(aw[ot][1], bx[nt][1], acc[ot][nt], 0, 0, 0);
      }

    // pack C into per-wave LDS tile [node][o], row stride 72 shorts
    #pragma unroll
    for (int ot = 0; ot < 4; ++ot)
      #pragma unroll
      for (int nt = 0; nt < 4; ++nt) {
        int node = nt * 16 + lr;
        int o = ot * 16 + (lh << 2);
        uint2 p;
        p.x = (unsigned)f2bf(acc[ot][nt][0]) | ((unsigned)f2bf(acc[ot][nt][1]) << 16);
        p.y = (unsigned)f2bf(acc[ot][nt][2]) | ((unsigned)f2bf(acc[ot][nt][3]) << 16);
        *(uint2*)(tl + node * 72 + o) = p;
      }

    // copy out: each instruction writes 8 complete 128B lines
    #pragma unroll
    for (int r8 = 0; r8 < 8; ++r8) {
      int node = r8 * 8 + (l >> 3);
      int c = (l & 7) << 3;
      uint4 v = *(const uint4*)(tl + node * 72 + c);
      *(uint4*)(Y + ((size_t)(n0 + node) * 25 + k) * 64 + c) = v;
    }

    #pragma unroll
    for (int ot = 0; ot < 4; ++ot)
      #pragma unroll
      for (int h = 0; h < 2; ++h)
        aw[ot][h] = awn[ot][h];
    k = kn;
  }
}

// ---------------- CSR build: histogram -> 3-stage parallel scan -> scatter ----------------
__global__ __launch_bounds__(256) void hist_kernel(
    const int* __restrict__ ei, int* __restrict__ cnt) {
  int e = blockIdx.x * 256 + threadIdx.x;
  atomicAdd(&cnt[ei[E_N + e]], 1);
}

__global__ __launch_bounds__(256) void scan1_kernel(
    const int* __restrict__ cnt, int* __restrict__ bsum) {
  __shared__ int red[256];
  int t = threadIdx.x;
  int j = blockIdx.x * 256 + t;
  red[t] = (j < N_N) ? cnt[j] : 0;
  __syncthreads();
  #pragma unroll
  for (int s = 128; s > 0; s >>= 1) {
    if (t < s) red[t] += red[t + s];
    __syncthreads();
  }
  if (t == 0) bsum[blockIdx.x] = red[0];
}

__global__ __launch_bounds__(256) void scan2_kernel(
    const int* __restrict__ bsum, int* __restrict__ bofs) {
  __shared__ int v[256];
  int t = threadIdx.x;
  v[t] = (t < SCAN_B) ? bsum[t] : 0;
  __syncthreads();
  if (t == 0) {
    int acc = 0;
    for (int i = 0; i < SCAN_B; ++i) { int c = v[i]; v[i] = acc; acc += c; }
  }
  __syncthreads();
  if (t < SCAN_B) bofs[t] = v[t];
}

__global__ __launch_bounds__(256) void scan3_kernel(
    int* __restrict__ cnt, const int* __restrict__ bofs,
    int* __restrict__ start) {
  __shared__ int v[2][256];
  int t = threadIdx.x;
  int j = blockIdx.x * 256 + t;
  int c = (j < N_N) ? cnt[j] : 0;
  v[0][t] = c;
  __syncthreads();
  int cur = 0;
  #pragma unroll
  for (int s = 1; s < 256; s <<= 1) {
    v[1 - cur][t] = (t >= s) ? v[cur][t] + v[cur][t - s] : v[cur][t];
    __syncthreads();
    cur = 1 - cur;
  }
  if (j < N_N) {
    int ex = bofs[blockIdx.x] + v[cur][t] - c;
    start[j] = ex;
    cnt[j] = ex;  // becomes the scatter cursor
    if (j == 0) start[N_N] = E_N;
  }
}

// recs: uint2 { src | I0<<16, q0 | q1<<16 }  (q = 16-bit fixed-point frac)
__global__ __launch_bounds__(256) void scatter_kernel(
    const float* __restrict__ ea, const int* __restrict__ ei,
    int* __restrict__ ofs, uint2* __restrict__ recs) {
  int e = blockIdx.x * 256 + threadIdx.x;
  int s = ei[e];
  int d = ei[E_N + e];
  float2 a = ((const float2*)ea)[e];
  float v0 = a.x * 4.0f, v1 = a.y * 4.0f;
  float b0f = fminf(fmaxf(floorf(v0), 0.0f), 3.0f);
  float b1f = fminf(fmaxf(floorf(v1), 0.0f), 3.0f);
  float f0 = v0 - b0f, f1 = v1 - b1f;
  int I0 = (int)b0f * 5 + (int)b1f;
  unsigned int q0 = (unsigned int)(f0 * 65535.0f + 0.5f);
  unsigned int q1 = (unsigned int)(f1 * 65535.0f + 0.5f);
  int pos = atomicAdd(&ofs[d], 1);
  uint2 rc;
  rc.x = (unsigned int)s | ((unsigned int)I0 << 16);
  rc.y = q0 | (q1 << 16);
  recs[pos] = rc;
}

// ---------------- agg: wave/node, 4 indep max chains, scalarized, recs software-pipelined ----------------
static __device__ __forceinline__ float emsg(
    const unsigned short* __restrict__ Y, unsigned int rx, unsigned int ry, int lane) {
  // rx, ry are wave-uniform (readfirstlane'd) -> address math on SALU
  int src = rx & 0xffff;
  int I0 = rx >> 16;
  float f0 = (float)(ry & 0xffff) * (1.0f / 65535.0f);
  float f1 = (float)(ry >> 16) * (1.0f / 65535.0f);
  const unsigned short* base = Y + (size_t)src * 1600 + I0 * 64 + lane;
  float y0 = bf2f(base[0]);
  float y1 = bf2f(base[64]);
  float y2 = bf2f(base[320]);
  float y3 = bf2f(base[384]);
  return (1.0f - f0) * ((1.0f - f1) * y0 + f1 * y1) +
         f0 * ((1.0f - f1) * y2 + f1 * y3);
}

__global__ __launch_bounds__(256) void agg_kernel(
    const unsigned short* __restrict__ Y, const uint2* __restrict__ recs,
    const int* __restrict__ start, const float* __restrict__ xin,
    const float* __restrict__ root, const float* __restrict__ bias,
    float* __restrict__ outp, int relu) {
  __shared__ float xl[4][64];
  const int w = threadIdx.x >> 6;
  const int lane = threadIdx.x & 63;
  const int n = blockIdx.x * 4 + w;
  xl[w][lane] = xin[((size_t)n << 6) + lane];
  __syncthreads();

  const int s = __builtin_amdgcn_readfirstlane(start[n]);
  const int e = __builtin_amdgcn_readfirstlane(start[n + 1]);
  const float NI = -__builtin_inff();
  float a0 = NI, a1 = NI, a2 = NI, a3 = NI;
  const int nfull = (e - s) >> 2;
  int j = s + (nfull << 2);
  if (nfull > 0) {
    // pipelined: group g+1's recs loads issue before group g's row-load waits
    uint2 c0 = recs[s], c1 = recs[s + 1], c2 = recs[s + 2], c3 = recs[s + 3];
    for (int g = 1; g < nfull; ++g) {
      const int jn = s + (g << 2);
      uint2 n0 = recs[jn], n1 = recs[jn + 1], n2 = recs[jn + 2], n3 = recs[jn + 3];
      unsigned x0 = __builtin_amdgcn_readfirstlane(c0.x), y0 = __builtin_amdgcn_readfirstlane(c0.y);
      unsigned x1 = __builtin_amdgcn_readfirstlane(c1.x), y1 = __builtin_amdgcn_readfirstlane(c1.y);
      unsigned x2 = __builtin_amdgcn_readfirstlane(c2.x), y2 = __builtin_amdgcn_readfirstlane(c2.y);
      unsigned x3 = __builtin_amdgcn_readfirstlane(c3.x), y3 = __builtin_amdgcn_readfirstlane(c3.y);
      a0 = fmaxf(a0, emsg(Y, x0, y0, lane));
      a1 = fmaxf(a1, emsg(Y, x1, y1, lane));
      a2 = fmaxf(a2, emsg(Y, x2, y2, lane));
      a3 = fmaxf(a3, emsg(Y, x3, y3, lane));
      c0 = n0; c1 = n1; c2 = n2; c3 = n3;
    }
    unsigned x0 = __builtin_amdgcn_readfirstlane(c0.x), y0 = __builtin_amdgcn_readfirstlane(c0.y);
    unsigned x1 = __builtin_amdgcn_readfirstlane(c1.x), y1 = __builtin_amdgcn_readfirstlane(c1.y);
    unsigned x2 = __builtin_amdgcn_readfirstlane(c2.x), y2 = __builtin_amdgcn_readfirstlane(c2.y);
    unsigned x3 = __builtin_amdgcn_readfirstlane(c3.x), y3 = __builtin_amdgcn_readfirstlane(c3.y);
    a0 = fmaxf(a0, emsg(Y, x0, y0, lane));
    a1 = fmaxf(a1, emsg(Y, x1, y1, lane));
    a2 = fmaxf(a2, emsg(Y, x2, y2, lane));
    a3 = fmaxf(a3, emsg(Y, x3, y3, lane));
  }
  for (; j < e; ++j) {
    uint2 rc = recs[j];
    unsigned rx = __builtin_amdgcn_readfirstlane(rc.x);
    unsigned ry = __builtin_amdgcn_readfirstlane(rc.y);
    a0 = fmaxf(a0, emsg(Y, rx, ry, lane));
  }
  float acc = fmaxf(fmaxf(a0, a1), fmaxf(a2, a3));
  if (s == e) acc = 0.0f;

  float r = bias[lane];
  #pragma unroll 8
  for (int i = 0; i < 64; ++i)
    r += xl[w][i] * root[(i << 6) + lane];
  r += acc;
  if (relu) r = fmaxf(r, 0.0f);
  outp[((size_t)n << 6) + lane] = r;
}

extern "C" void kernel_launch(void* const* d_in, const int* in_sizes, int n_in,
                              void* d_out, int out_size, void* d_ws, size_t ws_size,
                              hipStream_t stream) {
  const float* x = (const float*)d_in[0];
  const int* ei = (const int*)d_in[1];
  const float* ea = (const float*)d_in[2];
  const float* W1 = (const float*)d_in[3];
  const float* root1 = (const float*)d_in[4];
  const float* bias1 = (const float*)d_in[5];
  const float* W2 = (const float*)d_in[6];
  const float* root2 = (const float*)d_in[7];
  const float* bias2 = (const float*)d_in[8];
  float* out = (float*)d_out;

  const size_t yB = (size_t)N_N * 1600 * 2;        // 128,000,000
  const size_t rB = (size_t)E_N * 8;               //   5,120,000
  const size_t sB = (size_t)(N_N + 2) * 4;         //     160,008
  const size_t cB = (size_t)N_N * 4;               //     160,000
  const size_t wB = (size_t)2 * 25 * 64 * 64 * 2;  //     409,600
  const size_t bB = (size_t)1024 * 2;
  if (ws_size < yB + rB + sB + cB + wB + bB) return;

  char* p = (char*)d_ws;
  unsigned short* Y = (unsigned short*)p; p += yB;
  uint2* recs = (uint2*)p;                p += rB;
  int* startA = (int*)p;                  p += sB;
  int* cnt = (int*)p;                     p += cB;   // doubles as scatter cursor
  unsigned short* Wt = (unsigned short*)p; p += wB;  // Wt1 | Wt2
  int* bsum = (int*)p;                    p += 1024;
  int* bofs = (int*)p;
  float* h = out;  // layer-1 output lives in d_out; fully overwritten by layer 2

  unsigned short* Wt1 = Wt;
  unsigned short* Wt2 = Wt + (size_t)25 * 64 * 64;

  dim3 blk(256);

  // ---- CSR build (once, shared by both layers) + weight transposes (also zeroes cnt) ----
  wtrans_kernel<<<800, blk, 0, stream>>>(W1, W2, Wt, cnt);
  hist_kernel<<<E_N / 256, blk, 0, stream>>>(ei, cnt);
  scan1_kernel<<<SCAN_B, blk, 0, stream>>>(cnt, bsum);
  scan2_kernel<<<1, blk, 0, stream>>>(bsum, bofs);
  scan3_kernel<<<SCAN_B, blk, 0, stream>>>(cnt, bofs, startA);
  scatter_kernel<<<E_N / 256, blk, 0, stream>>>(ea, ei, cnt, recs);

  // ---- layer 1 ----
  ygemm_kernel<<<N_N / 64, blk, 0, stream>>>(x, Wt1, Y);
  agg_kernel<<<N_N / 4, blk, 0, stream>>>(Y, recs, startA, x, root1, bias1, h, 1);

  // ---- layer 2 ----
  ygemm_kernel<<<N_N / 64, blk, 0, stream>>>(h, Wt2, Y);
  agg_kernel<<<N_N / 4, blk, 0, stream>>>(Y, recs, startA, h, root2, bias2, out, 0);
}

// Round 15
// 255.317 us; speedup vs baseline: 2.6339x; 1.0213x over previous
//
#include <hip/hip_runtime.h>
#include <hip/hip_bf16.h>

#define E_N 640000
#define N_N 40000
#define SCAN_B 157  // ceil(40000/256)

typedef __attribute__((ext_vector_type(8))) short short8;
typedef __attribute__((ext_vector_type(4))) float f32x4;

static __device__ __forceinline__ unsigned short f2bf(float f) {
  __hip_bfloat16 h = __float2bfloat16(f);
  unsigned short u;
  __builtin_memcpy(&u, &h, 2);
  return u;
}
static __device__ __forceinline__ float bf2f(unsigned short u) {
  return __uint_as_float(((unsigned int)u) << 16);
}

// ---------------- Wt[layer][k][o][i] = bf16(W[k][i][o]); blocks 0..156 also zero cnt ----------------
__global__ __launch_bounds__(256) void wtrans_kernel(
    const float* __restrict__ W1, const float* __restrict__ W2,
    unsigned short* __restrict__ Wt, int* __restrict__ cnt) {
  if (blockIdx.x < SCAN_B) {
    int j = blockIdx.x * 256 + threadIdx.x;
    if (j < N_N) cnt[j] = 0;
  }
  int t = blockIdx.x * 256 + threadIdx.x;  // 0..204799
  int half = t >= 102400;
  int r = t - (half ? 102400 : 0);
  const float* W = half ? W2 : W1;
  int k = r >> 12, rr = r & 4095, o = rr >> 6, i = rr & 63;
  Wt[((size_t)half * 102400) + (k << 12) + (o << 6) + i] = f2bf(W[(k << 12) + (i << 6) + o]);
}

// ---------------- Y[n,k,o] via MFMA; 64-node tiles, per-wave k-loop + k+4 prefetch ----------------
// LDS-staged full-line writeout (kills L2 write-allocate RMW of Y).  [R9 proven form]
__global__ __launch_bounds__(256) void ygemm_kernel(
    const float* __restrict__ x, const unsigned short* __restrict__ Wt,
    unsigned short* __restrict__ Y) {
  __shared__ unsigned short tile[4][64 * 72];  // per-wave private, stride 144B
  const int n0 = blockIdx.x * 64;
  const int w = threadIdx.x >> 6;
  const int l = threadIdx.x & 63;
  const int lr = l & 15;
  const int lh = l >> 4;
  unsigned short* tl = tile[w];

  short8 bx[4][2];
  #pragma unroll
  for (int nt = 0; nt < 4; ++nt) {
    const float* xp = x + ((size_t)(n0 + nt * 16 + lr) << 6) + (lh << 3);
    #pragma unroll
    for (int h = 0; h < 2; ++h) {
      float4 lo = *(const float4*)(xp + h * 32);
      float4 hi = *(const float4*)(xp + h * 32 + 4);
      short8 b;
      b[0] = (short)f2bf(lo.x); b[1] = (short)f2bf(lo.y);
      b[2] = (short)f2bf(lo.z); b[3] = (short)f2bf(lo.w);
      b[4] = (short)f2bf(hi.x); b[5] = (short)f2bf(hi.y);
      b[6] = (short)f2bf(hi.z); b[7] = (short)f2bf(hi.w);
      bx[nt][h] = b;
    }
  }

  const f32x4 Z = {0.0f, 0.0f, 0.0f, 0.0f};

  int k = w;
  short8 aw[4][2];
  {
    const unsigned short* wk = Wt + ((size_t)k << 12);
    #pragma unroll
    for (int ot = 0; ot < 4; ++ot)
      #pragma unroll
      for (int h = 0; h < 2; ++h)
        aw[ot][h] = *(const short8*)(wk + ((ot * 16 + lr) << 6) + (h << 5) + (lh << 3));
  }

  while (k < 25) {
    const int kn = k + 4;
    short8 awn[4][2];
    if (kn < 25) {  // prefetch next-k fragments; overlaps MFMA + LDS phase below
      const unsigned short* wk = Wt + ((size_t)kn << 12);
      #pragma unroll
      for (int ot = 0; ot < 4; ++ot)
        #pragma unroll
        for (int h = 0; h < 2; ++h)
          awn[ot][h] = *(const short8*)(wk + ((ot * 16 + lr) << 6) + (h << 5) + (lh << 3));
    }

    f32x4 acc[4][4];
    #pragma unroll
    for (int ot = 0; ot < 4; ++ot)
      #pragma unroll
      for (int nt = 0; nt < 4; ++nt) {
        acc[ot][nt] = __builtin_amdgcn_mfma_f32_16x16x32_bf16(aw[ot][0], bx[nt][0], Z, 0, 0, 0);
        acc[ot][nt] = __builtin_amdgcn_mfma_f32_16x16x32_bf16(aw[ot][1], bx[nt][1], acc[ot][nt], 0, 0, 0);
      }

    // pack C into per-wave LDS tile [node][o], row stride 72 shorts
    #pragma unroll
    for (int ot = 0; ot < 4; ++ot)
      #pragma unroll
      for (int nt = 0; nt < 4; ++nt) {
        int node = nt * 16 + lr;
        int o = ot * 16 + (lh << 2);
        uint2 p;
        p.x = (unsigned)f2bf(acc[ot][nt][0]) | ((unsigned)f2bf(acc[ot][nt][1]) << 16);
        p.y = (unsigned)f2bf(acc[ot][nt][2]) | ((unsigned)f2bf(acc[ot][nt][3]) << 16);
        *(uint2*)(tl + node * 72 + o) = p;
      }

    // copy out: each instruction writes 8 complete 128B lines
    #pragma unroll
    for (int r8 = 0; r8 < 8; ++r8) {
      int node = r8 * 8 + (l >> 3);
      int c = (l & 7) << 3;
      uint4 v = *(const uint4*)(tl + node * 72 + c);
      *(uint4*)(Y + ((size_t)(n0 + node) * 25 + k) * 64 + c) = v;
    }

    #pragma unroll
    for (int ot = 0; ot < 4; ++ot)
      #pragma unroll
      for (int h = 0; h < 2; ++h)
        aw[ot][h] = awn[ot][h];
    k = kn;
  }
}

// ---------------- CSR build: histogram -> 3-stage parallel scan -> scatter ----------------
__global__ __launch_bounds__(256) void hist_kernel(
    const int* __restrict__ ei, int* __restrict__ cnt) {
  int e = blockIdx.x * 256 + threadIdx.x;
  atomicAdd(&cnt[ei[E_N + e]], 1);
}

__global__ __launch_bounds__(256) void scan1_kernel(
    const int* __restrict__ cnt, int* __restrict__ bsum) {
  __shared__ int red[256];
  int t = threadIdx.x;
  int j = blockIdx.x * 256 + t;
  red[t] = (j < N_N) ? cnt[j] : 0;
  __syncthreads();
  #pragma unroll
  for (int s = 128; s > 0; s >>= 1) {
    if (t < s) red[t] += red[t + s];
    __syncthreads();
  }
  if (t == 0) bsum[blockIdx.x] = red[0];
}

__global__ __launch_bounds__(256) void scan2_kernel(
    const int* __restrict__ bsum, int* __restrict__ bofs) {
  __shared__ int v[256];
  int t = threadIdx.x;
  v[t] = (t < SCAN_B) ? bsum[t] : 0;
  __syncthreads();
  if (t == 0) {
    int acc = 0;
    for (int i = 0; i < SCAN_B; ++i) { int c = v[i]; v[i] = acc; acc += c; }
  }
  __syncthreads();
  if (t < SCAN_B) bofs[t] = v[t];
}

__global__ __launch_bounds__(256) void scan3_kernel(
    int* __restrict__ cnt, const int* __restrict__ bofs,
    int* __restrict__ start) {
  __shared__ int v[2][256];
  int t = threadIdx.x;
  int j = blockIdx.x * 256 + t;
  int c = (j < N_N) ? cnt[j] : 0;
  v[0][t] = c;
  __syncthreads();
  int cur = 0;
  #pragma unroll
  for (int s = 1; s < 256; s <<= 1) {
    v[1 - cur][t] = (t >= s) ? v[cur][t] + v[cur][t - s] : v[cur][t];
    __syncthreads();
    cur = 1 - cur;
  }
  if (j < N_N) {
    int ex = bofs[blockIdx.x] + v[cur][t] - c;
    start[j] = ex;
    cnt[j] = ex;  // becomes the scatter cursor
    if (j == 0) start[N_N] = E_N;
  }
}

// recs: uint2 { src | I0<<16, q0 | q1<<16 }  (q = 16-bit fixed-point frac)
__global__ __launch_bounds__(256) void scatter_kernel(
    const float* __restrict__ ea, const int* __restrict__ ei,
    int* __restrict__ ofs, uint2* __restrict__ recs) {
  int e = blockIdx.x * 256 + threadIdx.x;
  int s = ei[e];
  int d = ei[E_N + e];
  float2 a = ((const float2*)ea)[e];
  float v0 = a.x * 4.0f, v1 = a.y * 4.0f;
  float b0f = fminf(fmaxf(floorf(v0), 0.0f), 3.0f);
  float b1f = fminf(fmaxf(floorf(v1), 0.0f), 3.0f);
  float f0 = v0 - b0f, f1 = v1 - b1f;
  int I0 = (int)b0f * 5 + (int)b1f;
  unsigned int q0 = (unsigned int)(f0 * 65535.0f + 0.5f);
  unsigned int q1 = (unsigned int)(f1 * 65535.0f + 0.5f);
  int pos = atomicAdd(&ofs[d], 1);
  uint2 rc;
  rc.x = (unsigned int)s | ((unsigned int)I0 << 16);
  rc.y = q0 | (q1 << 16);
  recs[pos] = rc;
}

// ---------------- agg: 2 nodes per wave (8 chains, 32 lines in flight), scalarized ----------------
static __device__ __forceinline__ float emsg(
    const unsigned short* __restrict__ Y, unsigned int rx, unsigned int ry, int lane) {
  // rx, ry are wave-uniform (readfirstlane'd) -> address math on SALU
  int src = rx & 0xffff;
  int I0 = rx >> 16;
  float f0 = (float)(ry & 0xffff) * (1.0f / 65535.0f);
  float f1 = (float)(ry >> 16) * (1.0f / 65535.0f);
  const unsigned short* base = Y + (size_t)src * 1600 + I0 * 64 + lane;
  float y0 = bf2f(base[0]);
  float y1 = bf2f(base[64]);
  float y2 = bf2f(base[320]);
  float y3 = bf2f(base[384]);
  return (1.0f - f0) * ((1.0f - f1) * y0 + f1 * y1) +
         f0 * ((1.0f - f1) * y2 + f1 * y3);
}

// 4-wide group step for one node: load group recs, scalarize, update 4 chains
#define GRP4(J, A0, A1, A2, A3)                                                 \
  {                                                                             \
    uint2 r0 = recs[(J)];                                                       \
    uint2 r1 = recs[(J) + 1];                                                   \
    uint2 r2 = recs[(J) + 2];                                                   \
    uint2 r3 = recs[(J) + 3];                                                   \
    unsigned q0x = __builtin_amdgcn_readfirstlane(r0.x);                        \
    unsigned q0y = __builtin_amdgcn_readfirstlane(r0.y);                        \
    unsigned q1x = __builtin_amdgcn_readfirstlane(r1.x);                        \
    unsigned q1y = __builtin_amdgcn_readfirstlane(r1.y);                        \
    unsigned q2x = __builtin_amdgcn_readfirstlane(r2.x);                        \
    unsigned q2y = __builtin_amdgcn_readfirstlane(r2.y);                        \
    unsigned q3x = __builtin_amdgcn_readfirstlane(r3.x);                        \
    unsigned q3y = __builtin_amdgcn_readfirstlane(r3.y);                        \
    A0 = fmaxf(A0, emsg(Y, q0x, q0y, lane));                                    \
    A1 = fmaxf(A1, emsg(Y, q1x, q1y, lane));                                    \
    A2 = fmaxf(A2, emsg(Y, q2x, q2y, lane));                                    \
    A3 = fmaxf(A3, emsg(Y, q3x, q3y, lane));                                    \
  }

__global__ __launch_bounds__(256) void agg_kernel(
    const unsigned short* __restrict__ Y, const uint2* __restrict__ recs,
    const int* __restrict__ start, const float* __restrict__ xin,
    const float* __restrict__ root, const float* __restrict__ bias,
    float* __restrict__ outp, int relu) {
  const int w = threadIdx.x >> 6;
  const int lane = threadIdx.x & 63;
  const int na = blockIdx.x * 8 + w * 2;
  const int nb = na + 1;

  const int sa = __builtin_amdgcn_readfirstlane(start[na]);
  const int ea = __builtin_amdgcn_readfirstlane(start[na + 1]);
  const int sb = __builtin_amdgcn_readfirstlane(start[nb]);
  const int eb = __builtin_amdgcn_readfirstlane(start[nb + 1]);

  const float NI = -__builtin_inff();
  float aa0 = NI, aa1 = NI, aa2 = NI, aa3 = NI;
  float ab0 = NI, ab1 = NI, ab2 = NI, ab3 = NI;
  int ja = sa, jb = sb;

  // joint main loop: 8 rec loads + 32 row loads in flight before dependent waits
  while (ja + 4 <= ea && jb + 4 <= eb) {
    uint2 r0 = recs[ja];
    uint2 r1 = recs[ja + 1];
    uint2 r2 = recs[ja + 2];
    uint2 r3 = recs[ja + 3];
    uint2 t0 = recs[jb];
    uint2 t1 = recs[jb + 1];
    uint2 t2 = recs[jb + 2];
    uint2 t3 = recs[jb + 3];
    unsigned q0x = __builtin_amdgcn_readfirstlane(r0.x), q0y = __builtin_amdgcn_readfirstlane(r0.y);
    unsigned q1x = __builtin_amdgcn_readfirstlane(r1.x), q1y = __builtin_amdgcn_readfirstlane(r1.y);
    unsigned q2x = __builtin_amdgcn_readfirstlane(r2.x), q2y = __builtin_amdgcn_readfirstlane(r2.y);
    unsigned q3x = __builtin_amdgcn_readfirstlane(r3.x), q3y = __builtin_amdgcn_readfirstlane(r3.y);
    unsigned u0x = __builtin_amdgcn_readfirstlane(t0.x), u0y = __builtin_amdgcn_readfirstlane(t0.y);
    unsigned u1x = __builtin_amdgcn_readfirstlane(t1.x), u1y = __builtin_amdgcn_readfirstlane(t1.y);
    unsigned u2x = __builtin_amdgcn_readfirstlane(t2.x), u2y = __builtin_amdgcn_readfirstlane(t2.y);
    unsigned u3x = __builtin_amdgcn_readfirstlane(t3.x), u3y = __builtin_amdgcn_readfirstlane(t3.y);
    aa0 = fmaxf(aa0, emsg(Y, q0x, q0y, lane));
    aa1 = fmaxf(aa1, emsg(Y, q1x, q1y, lane));
    aa2 = fmaxf(aa2, emsg(Y, q2x, q2y, lane));
    aa3 = fmaxf(aa3, emsg(Y, q3x, q3y, lane));
    ab0 = fmaxf(ab0, emsg(Y, u0x, u0y, lane));
    ab1 = fmaxf(ab1, emsg(Y, u1x, u1y, lane));
    ab2 = fmaxf(ab2, emsg(Y, u2x, u2y, lane));
    ab3 = fmaxf(ab3, emsg(Y, u3x, u3y, lane));
    ja += 4;
    jb += 4;
  }
  // node-a drain
  for (; ja + 4 <= ea; ja += 4) GRP4(ja, aa0, aa1, aa2, aa3);
  for (; ja < ea; ++ja) {
    uint2 rc = recs[ja];
    unsigned rx = __builtin_amdgcn_readfirstlane(rc.x);
    unsigned ry = __builtin_amdgcn_readfirstlane(rc.y);
    aa0 = fmaxf(aa0, emsg(Y, rx, ry, lane));
  }
  // node-b drain
  for (; jb + 4 <= eb; jb += 4) GRP4(jb, ab0, ab1, ab2, ab3);
  for (; jb < eb; ++jb) {
    uint2 rc = recs[jb];
    unsigned rx = __builtin_amdgcn_readfirstlane(rc.x);
    unsigned ry = __builtin_amdgcn_readfirstlane(rc.y);
    ab0 = fmaxf(ab0, emsg(Y, rx, ry, lane));
  }

  float acca = fmaxf(fmaxf(aa0, aa1), fmaxf(aa2, aa3));
  float accb = fmaxf(fmaxf(ab0, ab1), fmaxf(ab2, ab3));
  if (sa == ea) acca = 0.0f;
  if (sb == eb) accb = 0.0f;

  // epilogue for both nodes; x rows via LDS (wave-private slots)
  __shared__ float xl[4][2][64];
  xl[w][0][lane] = xin[((size_t)na << 6) + lane];
  xl[w][1][lane] = xin[((size_t)nb << 6) + lane];
  const float bi = bias[lane];
  float ra = bi, rb = bi;
  #pragma unroll 8
  for (int i = 0; i < 64; ++i) {
    float rv = root[(i << 6) + lane];
    ra += xl[w][0][i] * rv;
    rb += xl[w][1][i] * rv;
  }
  ra += acca;
  rb += accb;
  if (relu) {
    ra = fmaxf(ra, 0.0f);
    rb = fmaxf(rb, 0.0f);
  }
  outp[((size_t)na << 6) + lane] = ra;
  outp[((size_t)nb << 6) + lane] = rb;
}

extern "C" void kernel_launch(void* const* d_in, const int* in_sizes, int n_in,
                              void* d_out, int out_size, void* d_ws, size_t ws_size,
                              hipStream_t stream) {
  const float* x = (const float*)d_in[0];
  const int* ei = (const int*)d_in[1];
  const float* ea = (const float*)d_in[2];
  const float* W1 = (const float*)d_in[3];
  const float* root1 = (const float*)d_in[4];
  const float* bias1 = (const float*)d_in[5];
  const float* W2 = (const float*)d_in[6];
  const float* root2 = (const float*)d_in[7];
  const float* bias2 = (const float*)d_in[8];
  float* out = (float*)d_out;

  const size_t yB = (size_t)N_N * 1600 * 2;        // 128,000,000
  const size_t rB = (size_t)E_N * 8;               //   5,120,000
  const size_t sB = (size_t)(N_N + 2) * 4;         //     160,008
  const size_t cB = (size_t)N_N * 4;               //     160,000
  const size_t wB = (size_t)2 * 25 * 64 * 64 * 2;  //     409,600
  const size_t bB = (size_t)1024 * 2;
  if (ws_size < yB + rB + sB + cB + wB + bB) return;

  char* p = (char*)d_ws;
  unsigned short* Y = (unsigned short*)p; p += yB;
  uint2* recs = (uint2*)p;                p += rB;
  int* startA = (int*)p;                  p += sB;
  int* cnt = (int*)p;                     p += cB;   // doubles as scatter cursor
  unsigned short* Wt = (unsigned short*)p; p += wB;  // Wt1 | Wt2
  int* bsum = (int*)p;                    p += 1024;
  int* bofs = (int*)p;
  float* h = out;  // layer-1 output lives in d_out; fully overwritten by layer 2

  unsigned short* Wt1 = Wt;
  unsigned short* Wt2 = Wt + (size_t)25 * 64 * 64;

  dim3 blk(256);

  // ---- CSR build (once, shared by both layers) + weight transposes (also zeroes cnt) ----
  wtrans_kernel<<<800, blk, 0, stream>>>(W1, W2, Wt, cnt);
  hist_kernel<<<E_N / 256, blk, 0, stream>>>(ei, cnt);
  scan1_kernel<<<SCAN_B, blk, 0, stream>>>(cnt, bsum);
  scan2_kernel<<<1, blk, 0, stream>>>(bsum, bofs);
  scan3_kernel<<<SCAN_B, blk, 0, stream>>>(cnt, bofs, startA);
  scatter_kernel<<<E_N / 256, blk, 0, stream>>>(ea, ei, cnt, recs);

  // ---- layer 1 ----
  ygemm_kernel<<<N_N / 64, blk, 0, stream>>>(x, Wt1, Y);
  agg_kernel<<<N_N / 8, blk, 0, stream>>>(Y, recs, startA, x, root1, bias1, h, 1);

  // ---- layer 2 ----
  ygemm_kernel<<<N_N / 64, blk, 0, stream>>>(h, Wt2, Y);
  agg_kernel<<<N_N / 8, blk, 0, stream>>>(Y, recs, startA, h, root2, bias2, out, 0);
}